// Round 1
// baseline (63191.833 us; speedup 1.0000x reference)
//
#include <hip/hip_runtime.h>

#define H 256
#define B 128
#define T_ENC 240
#define T_FUT 360
#define NKEYS 241

__device__ __forceinline__ float sigm(float x) { return 1.f / (1.f + __expf(-x)); }
__device__ __forceinline__ float ftanh(float x) { float e = __expf(2.f * x); return 1.f - 2.f / (e + 1.f); }

// ---------------- CNN ----------------
template<int IC, int OC, int IN_HW, int OUT_HW>
__global__ void conv_relu(const float* __restrict__ in, const float* __restrict__ w,
                          const float* __restrict__ bias, float* __restrict__ out)
{
    int idx = blockIdx.x * blockDim.x + threadIdx.x;
    constexpr int total = B * OC * OUT_HW * OUT_HW;
    if (idx >= total) return;
    int x  = idx % OUT_HW;
    int y  = (idx / OUT_HW) % OUT_HW;
    int oc = (idx / (OUT_HW * OUT_HW)) % OC;
    int b  = idx / (OUT_HW * OUT_HW * OC);
    float acc = bias[oc];
    const float* wp = w + (size_t)oc * IC * 9;
    const float* ip = in + (size_t)b * IC * IN_HW * IN_HW;
    for (int ic = 0; ic < IC; ++ic) {
        const float* ipc = ip + (size_t)ic * IN_HW * IN_HW;
        const float* wpc = wp + ic * 9;
        #pragma unroll
        for (int ky = 0; ky < 3; ++ky) {
            int iy = 2 * y - 1 + ky;
            if ((unsigned)iy >= (unsigned)IN_HW) continue;
            #pragma unroll
            for (int kx = 0; kx < 3; ++kx) {
                int ix = 2 * x - 1 + kx;
                if ((unsigned)ix >= (unsigned)IN_HW) continue;
                acc += ipc[iy * IN_HW + ix] * wpc[ky * 3 + kx];
            }
        }
    }
    out[idx] = fmaxf(acc, 0.f);
}

// pooled mean over 8x8 then env_feat = pooled @ ef_w^T + ef_b -> keys[b,240,:]
__global__ void pool_ef(const float* __restrict__ conv3, const float* __restrict__ ef_w,
                        const float* __restrict__ ef_b, float* __restrict__ keys)
{
    int b = blockIdx.x, tid = threadIdx.x;
    __shared__ float pooled[128];
    if (tid < 128) {
        const float* p = conv3 + (size_t)(b * 128 + tid) * 64;
        float s = 0.f;
        #pragma unroll 8
        for (int i = 0; i < 64; ++i) s += p[i];
        pooled[tid] = s * (1.f / 64.f);
    }
    __syncthreads();
    float acc = ef_b[tid];
    const float* wr = ef_w + (size_t)tid * 128;
    for (int c = 0; c < 128; ++c) acc += pooled[c] * wr[c];
    keys[((size_t)b * NKEYS + 240) * H + tid] = acc;
}

// ---------------- init ----------------
__global__ void zero_init(float* __restrict__ h0, float* __restrict__ c0,
                          float* __restrict__ h1, float* __restrict__ c1)
{
    int i = blockIdx.x * 256 + threadIdx.x;
    if (i < B * H) { h0[i] = 0.f; c0[i] = 0.f; h1[i] = 0.f; c1[i] = 0.f; }
}

__global__ void dec_init(const float* __restrict__ h0f, const float* __restrict__ c0,
                         const float* __restrict__ h1f, const float* __restrict__ c1,
                         const float* __restrict__ hist,
                         float* __restrict__ hd1, float* __restrict__ cd1,
                         float* __restrict__ hd2, float* __restrict__ cd2,
                         float* __restrict__ curr)
{
    int i = blockIdx.x * 256 + threadIdx.x;
    if (i < B * H) { hd1[i] = h0f[i]; cd1[i] = c0[i]; hd2[i] = h1f[i]; cd2[i] = c1[i]; }
    if (i < B * 2) {
        int b = i >> 1, c = i & 1;
        curr[i] = hist[((size_t)b * T_ENC + (T_ENC - 1)) * 2 + c];
    }
}

// ---------------- encoder phase: layer0 step p || layer1 step p-1 ----------------
__global__ void enc_phase(int p,
    const float* __restrict__ hist,
    const float* __restrict__ Wih0, const float* __restrict__ Whh0,
    const float* __restrict__ bih0, const float* __restrict__ bhh0,
    const float* __restrict__ Wih1, const float* __restrict__ Whh1,
    const float* __restrict__ bih1, const float* __restrict__ bhh1,
    float* __restrict__ h0buf, float* __restrict__ c0,
    float* __restrict__ h1buf, float* __restrict__ c1,
    float* __restrict__ ring, float* __restrict__ keys)
{
    int blk = blockIdx.x, tid = threadIdx.x;
    int b = tid & 127, jj = tid >> 7;
    if (blk < 128) {
        if (p >= T_ENC) return;
        int j = blk * 2 + jj;
        const float* hr = h0buf + (size_t)(p & 1) * (B * H) + b * H;
        float* hw = h0buf + (size_t)((p + 1) & 1) * (B * H);
        float g[4];
        #pragma unroll
        for (int q = 0; q < 4; ++q) g[q] = bih0[q * H + j] + bhh0[q * H + j];
        float x0 = hist[((size_t)b * T_ENC + p) * 2 + 0];
        float x1 = hist[((size_t)b * T_ENC + p) * 2 + 1];
        #pragma unroll
        for (int q = 0; q < 4; ++q)
            g[q] += x0 * Wih0[(q * H + j) * 2 + 0] + x1 * Wih0[(q * H + j) * 2 + 1];
        const float4* h4 = reinterpret_cast<const float4*>(hr);
        const float4* w0 = reinterpret_cast<const float4*>(Whh0 + (size_t)(0 * H + j) * H);
        const float4* w1 = reinterpret_cast<const float4*>(Whh0 + (size_t)(1 * H + j) * H);
        const float4* w2 = reinterpret_cast<const float4*>(Whh0 + (size_t)(2 * H + j) * H);
        const float4* w3 = reinterpret_cast<const float4*>(Whh0 + (size_t)(3 * H + j) * H);
        for (int k = 0; k < H / 4; ++k) {
            float4 hh = h4[k];
            float4 a = w0[k]; g[0] += hh.x * a.x + hh.y * a.y + hh.z * a.z + hh.w * a.w;
            float4 bq = w1[k]; g[1] += hh.x * bq.x + hh.y * bq.y + hh.z * bq.z + hh.w * bq.w;
            float4 cq = w2[k]; g[2] += hh.x * cq.x + hh.y * cq.y + hh.z * cq.z + hh.w * cq.w;
            float4 dq = w3[k]; g[3] += hh.x * dq.x + hh.y * dq.y + hh.z * dq.z + hh.w * dq.w;
        }
        float cold = c0[b * H + j];
        float iv = sigm(g[0]), fv = sigm(g[1]), gv = ftanh(g[2]), ov = sigm(g[3]);
        float cn = fv * cold + iv * gv;
        float hn = ov * ftanh(cn);
        c0[b * H + j] = cn;
        hw[b * H + j] = hn;
        ring[(size_t)(p & 1) * (B * H) + b * H + j] = hn;
    } else {
        if (p < 1) return;
        int j = (blk - 128) * 2 + jj;
        int tt = p - 1;
        const float* xr = ring + (size_t)((p - 1) & 1) * (B * H) + b * H;
        const float* hr = h1buf + (size_t)((p - 1) & 1) * (B * H) + b * H;
        float* hw = h1buf + (size_t)(p & 1) * (B * H);
        float g[4];
        #pragma unroll
        for (int q = 0; q < 4; ++q) g[q] = bih1[q * H + j] + bhh1[q * H + j];
        const float4* x4 = reinterpret_cast<const float4*>(xr);
        const float4* h4 = reinterpret_cast<const float4*>(hr);
        const float4* wi0 = reinterpret_cast<const float4*>(Wih1 + (size_t)(0 * H + j) * H);
        const float4* wi1 = reinterpret_cast<const float4*>(Wih1 + (size_t)(1 * H + j) * H);
        const float4* wi2 = reinterpret_cast<const float4*>(Wih1 + (size_t)(2 * H + j) * H);
        const float4* wi3 = reinterpret_cast<const float4*>(Wih1 + (size_t)(3 * H + j) * H);
        const float4* wh0 = reinterpret_cast<const float4*>(Whh1 + (size_t)(0 * H + j) * H);
        const float4* wh1 = reinterpret_cast<const float4*>(Whh1 + (size_t)(1 * H + j) * H);
        const float4* wh2 = reinterpret_cast<const float4*>(Whh1 + (size_t)(2 * H + j) * H);
        const float4* wh3 = reinterpret_cast<const float4*>(Whh1 + (size_t)(3 * H + j) * H);
        for (int k = 0; k < H / 4; ++k) {
            float4 xx = x4[k], hh = h4[k];
            float4 a;
            a = wi0[k]; g[0] += xx.x * a.x + xx.y * a.y + xx.z * a.z + xx.w * a.w;
            a = wi1[k]; g[1] += xx.x * a.x + xx.y * a.y + xx.z * a.z + xx.w * a.w;
            a = wi2[k]; g[2] += xx.x * a.x + xx.y * a.y + xx.z * a.z + xx.w * a.w;
            a = wi3[k]; g[3] += xx.x * a.x + xx.y * a.y + xx.z * a.z + xx.w * a.w;
            a = wh0[k]; g[0] += hh.x * a.x + hh.y * a.y + hh.z * a.z + hh.w * a.w;
            a = wh1[k]; g[1] += hh.x * a.x + hh.y * a.y + hh.z * a.z + hh.w * a.w;
            a = wh2[k]; g[2] += hh.x * a.x + hh.y * a.y + hh.z * a.z + hh.w * a.w;
            a = wh3[k]; g[3] += hh.x * a.x + hh.y * a.y + hh.z * a.z + hh.w * a.w;
        }
        float cold = c1[b * H + j];
        float iv = sigm(g[0]), fv = sigm(g[1]), gv = ftanh(g[2]), ov = sigm(g[3]);
        float cn = fv * cold + iv * gv;
        float hn = ov * ftanh(cn);
        c1[b * H + j] = cn;
        hw[b * H + j] = hn;
        keys[((size_t)b * NKEYS + tt) * H + j] = hn;
    }
}

// ---------------- keys_proj = keys @ Wk^T + aW_b ----------------
__global__ void keysproj(const float* __restrict__ keys, const float* __restrict__ aW_w,
                         const float* __restrict__ aW_b, float* __restrict__ kp)
{
    __shared__ float ks[32][H];
    int row0 = blockIdx.x * 32, tid = threadIdx.x;
    for (int i = tid; i < 32 * H; i += 256) {
        int r = i / H, h = i % H;
        ks[r][h] = keys[(size_t)(row0 + r) * H + h];
    }
    __syncthreads();
    int g = tid;
    const float4* w4 = reinterpret_cast<const float4*>(aW_w + (size_t)g * (2 * H) + H);
    float bias = aW_b[g];
    for (int r = 0; r < 32; ++r) {
        float acc = bias;
        const float4* k4 = reinterpret_cast<const float4*>(ks[r]);
        for (int k = 0; k < H / 4; ++k) {
            float4 a = k4[k], w = w4[k];
            acc += a.x * w.x + a.y * w.y + a.z * w.z + a.w * w.w;
        }
        kp[(size_t)(row0 + r) * H + g] = acc;
    }
}

// ---------------- decoder: attention (+ curr update for step t-1) ----------------
__global__ void dec_attn(int t, const float* __restrict__ keys, const float* __restrict__ kp,
                         const float* __restrict__ aW_w, const float* __restrict__ av_w,
                         const float* __restrict__ av_b, const float* __restrict__ o_w,
                         const float* __restrict__ o_b, const float* __restrict__ hd2_r,
                         float* __restrict__ curr, float* __restrict__ ctx,
                         float* __restrict__ preds)
{
    int b = blockIdx.x, tid = threadIdx.x;
    __shared__ float h2[H], qv[H], av[H], al[NKEYS], red[256];
    h2[tid] = hd2_r[b * H + tid];
    av[tid] = av_w[tid];
    __syncthreads();
    if (t > 0 && tid < 2) {
        float acc = o_b[tid];
        const float* wr = o_w + tid * H;
        for (int h = 0; h < H; ++h) acc += h2[h] * wr[h];
        float c = curr[b * 2 + tid] + acc;
        curr[b * 2 + tid] = c;
        preds[((size_t)b * T_FUT + (t - 1)) * 2 + tid] = c;
    }
    // q = hd2 @ Wq^T (Wq = aW_w[:, :H])
    {
        float acc = 0.f;
        const float4* w4 = reinterpret_cast<const float4*>(aW_w + (size_t)tid * (2 * H));
        const float4* h4 = reinterpret_cast<const float4*>(h2);
        for (int k = 0; k < H / 4; ++k) {
            float4 w = w4[k], hh = h4[k];
            acc += w.x * hh.x + w.y * hh.y + w.z * hh.z + w.w * hh.w;
        }
        qv[tid] = acc;
    }
    __syncthreads();
    float e = -3.4e38f;
    if (tid < NKEYS) {
        float acc = av_b[0];
        const float4* kr = reinterpret_cast<const float4*>(kp + ((size_t)b * NKEYS + tid) * H);
        const float4* q4 = reinterpret_cast<const float4*>(qv);
        const float4* a4 = reinterpret_cast<const float4*>(av);
        for (int k = 0; k < H / 4; ++k) {
            float4 kk = kr[k], qq = q4[k], aa = a4[k];
            acc += aa.x * ftanh(qq.x + kk.x) + aa.y * ftanh(qq.y + kk.y)
                 + aa.z * ftanh(qq.z + kk.z) + aa.w * ftanh(qq.w + kk.w);
        }
        e = acc;
    }
    red[tid] = e; __syncthreads();
    for (int s = 128; s > 0; s >>= 1) { if (tid < s) red[tid] = fmaxf(red[tid], red[tid + s]); __syncthreads(); }
    float m = red[0]; __syncthreads();
    float ex = (tid < NKEYS) ? __expf(e - m) : 0.f;
    red[tid] = ex; __syncthreads();
    for (int s = 128; s > 0; s >>= 1) { if (tid < s) red[tid] += red[tid + s]; __syncthreads(); }
    float inv = 1.f / red[0];
    if (tid < NKEYS) al[tid] = ex * inv;
    __syncthreads();
    {
        float acc = 0.f;
        const float* kb = keys + (size_t)b * NKEYS * H + tid;
        #pragma unroll 4
        for (int k = 0; k < NKEYS; ++k) acc += al[k] * kb[(size_t)k * H];
        ctx[b * H + tid] = acc;
    }
}

// ---------------- decoder cell 0 (input = [curr, ctx], K = 258) ----------------
__global__ void dec_cell0(const float* __restrict__ Wih, const float* __restrict__ Whh,
                          const float* __restrict__ bih, const float* __restrict__ bhh,
                          const float* __restrict__ curr, const float* __restrict__ ctx,
                          const float* __restrict__ hd1_r, float* __restrict__ hd1_w,
                          float* __restrict__ cd1)
{
    int j = blockIdx.x, b = threadIdx.x;
    float g[4];
    #pragma unroll
    for (int q = 0; q < 4; ++q) g[q] = bih[q * H + j] + bhh[q * H + j];
    float u0 = curr[b * 2 + 0], u1 = curr[b * 2 + 1];
    #pragma unroll
    for (int q = 0; q < 4; ++q) {
        const float* wr = Wih + (size_t)(q * H + j) * 258;
        g[q] += u0 * wr[0] + u1 * wr[1];
    }
    const float* cx = ctx + (size_t)b * H;
    const float* hr = hd1_r + (size_t)b * H;
    for (int k = 0; k < H; k += 4) {
        float4 c4 = *reinterpret_cast<const float4*>(cx + k);
        float4 h4 = *reinterpret_cast<const float4*>(hr + k);
        #pragma unroll
        for (int q = 0; q < 4; ++q) {
            const float* wi = Wih + (size_t)(q * H + j) * 258 + 2 + k;
            const float* wh = Whh + (size_t)(q * H + j) * H + k;
            g[q] += c4.x * wi[0] + c4.y * wi[1] + c4.z * wi[2] + c4.w * wi[3]
                  + h4.x * wh[0] + h4.y * wh[1] + h4.z * wh[2] + h4.w * wh[3];
        }
    }
    float cold = cd1[b * H + j];
    float iv = sigm(g[0]), fv = sigm(g[1]), gv = ftanh(g[2]), ov = sigm(g[3]);
    float cn = fv * cold + iv * gv;
    cd1[b * H + j] = cn;
    hd1_w[b * H + j] = ov * ftanh(cn);
}

// ---------------- decoder cell 1 (input = hd1_new, K = 256) ----------------
__global__ void dec_cell1(const float* __restrict__ Wih, const float* __restrict__ Whh,
                          const float* __restrict__ bih, const float* __restrict__ bhh,
                          const float* __restrict__ xin, const float* __restrict__ hrec,
                          float* __restrict__ hw, float* __restrict__ cc)
{
    int j = blockIdx.x, b = threadIdx.x;
    float g[4];
    #pragma unroll
    for (int q = 0; q < 4; ++q) g[q] = bih[q * H + j] + bhh[q * H + j];
    const float* xr = xin + (size_t)b * H;
    const float* hr = hrec + (size_t)b * H;
    for (int k = 0; k < H; k += 4) {
        float4 x4 = *reinterpret_cast<const float4*>(xr + k);
        float4 h4 = *reinterpret_cast<const float4*>(hr + k);
        #pragma unroll
        for (int q = 0; q < 4; ++q) {
            const float4 wx = *reinterpret_cast<const float4*>(Wih + (size_t)(q * H + j) * H + k);
            const float4 wh = *reinterpret_cast<const float4*>(Whh + (size_t)(q * H + j) * H + k);
            g[q] += x4.x * wx.x + x4.y * wx.y + x4.z * wx.z + x4.w * wx.w
                  + h4.x * wh.x + h4.y * wh.y + h4.z * wh.z + h4.w * wh.w;
        }
    }
    float cold = cc[b * H + j];
    float iv = sigm(g[0]), fv = sigm(g[1]), gv = ftanh(g[2]), ov = sigm(g[3]);
    float cn = fv * cold + iv * gv;
    cc[b * H + j] = cn;
    hw[b * H + j] = ov * ftanh(cn);
}

// ---------------- final curr update (step 359 output) ----------------
__global__ void final_out(const float* __restrict__ hd2_r, const float* __restrict__ o_w,
                          const float* __restrict__ o_b, const float* __restrict__ curr,
                          float* __restrict__ preds)
{
    int tid = threadIdx.x;
    int b = tid >> 1, c = tid & 1;
    float acc = o_b[c];
    const float* wr = o_w + c * H;
    const float* h = hd2_r + (size_t)b * H;
    for (int k = 0; k < H; ++k) acc += h[k] * wr[k];
    preds[((size_t)b * T_FUT + (T_FUT - 1)) * 2 + c] = curr[b * 2 + c] + acc;
}

extern "C" void kernel_launch(void* const* d_in, const int* in_sizes, int n_in,
                              void* d_out, int out_size, void* d_ws, size_t ws_size,
                              hipStream_t stream)
{
    const float* hist   = (const float*)d_in[0];
    const float* env    = (const float*)d_in[1];
    const float* e0_Wih = (const float*)d_in[2];
    const float* e0_Whh = (const float*)d_in[3];
    const float* e0_bih = (const float*)d_in[4];
    const float* e0_bhh = (const float*)d_in[5];
    const float* e1_Wih = (const float*)d_in[6];
    const float* e1_Whh = (const float*)d_in[7];
    const float* e1_bih = (const float*)d_in[8];
    const float* e1_bhh = (const float*)d_in[9];
    const float* c1w = (const float*)d_in[10];
    const float* c1b = (const float*)d_in[11];
    const float* c2w = (const float*)d_in[12];
    const float* c2b = (const float*)d_in[13];
    const float* c3w = (const float*)d_in[14];
    const float* c3b = (const float*)d_in[15];
    const float* ef_w = (const float*)d_in[16];
    const float* ef_b = (const float*)d_in[17];
    const float* aW_w = (const float*)d_in[18];
    const float* aW_b = (const float*)d_in[19];
    const float* av_w = (const float*)d_in[20];
    const float* av_b = (const float*)d_in[21];
    const float* d0_Wih = (const float*)d_in[22];
    const float* d0_Whh = (const float*)d_in[23];
    const float* d0_bih = (const float*)d_in[24];
    const float* d0_bhh = (const float*)d_in[25];
    const float* d1_Wih = (const float*)d_in[26];
    const float* d1_Whh = (const float*)d_in[27];
    const float* d1_bih = (const float*)d_in[28];
    const float* d1_bhh = (const float*)d_in[29];
    const float* o_w = (const float*)d_in[30];
    const float* o_b = (const float*)d_in[31];

    float* preds = (float*)d_out;
    float* ws = (float*)d_ws;

    // workspace layout (floats). kp overlaps the conv scratch (kp written after convs done).
    const size_t KP_F = (size_t)B * NKEYS * H;       // 7,897,088
    float* kp    = ws;
    float* convA = ws;                               // 4,194,304
    float* convB = ws + 4194304;                     // 2,097,152
    float* convC = ws + 6291456;                     // 1,048,576
    size_t off = KP_F;
    float* keys  = ws + off; off += KP_F;
    const size_t BH = (size_t)B * H;
    float* h0buf = ws + off; off += 2 * BH;
    float* c0    = ws + off; off += BH;
    float* h1buf = ws + off; off += 2 * BH;
    float* c1    = ws + off; off += BH;
    float* ring  = ws + off; off += 2 * BH;
    float* hd1   = ws + off; off += 2 * BH;
    float* cd1   = ws + off; off += BH;
    float* hd2   = ws + off; off += 2 * BH;
    float* cd2   = ws + off; off += BH;
    float* ctx   = ws + off; off += BH;
    float* curr  = ws + off; off += (size_t)B * 2;

    // ---- init state ----
    zero_init<<<(B * H + 255) / 256, 256, 0, stream>>>(h0buf, c0, h1buf, c1);

    // ---- CNN branch ----
    conv_relu<18, 32, 64, 32><<<(B * 32 * 32 * 32) / 256, 256, 0, stream>>>(env, c1w, c1b, convA);
    conv_relu<32, 64, 32, 16><<<(B * 64 * 16 * 16) / 256, 256, 0, stream>>>(convA, c2w, c2b, convB);
    conv_relu<64, 128, 16, 8><<<(B * 128 * 8 * 8) / 256, 256, 0, stream>>>(convB, c3w, c3b, convC);
    pool_ef<<<B, 256, 0, stream>>>(convC, ef_w, ef_b, keys);

    // ---- encoder: 241 pipelined phases ----
    for (int p = 0; p <= T_ENC; ++p) {
        enc_phase<<<256, 256, 0, stream>>>(p, hist,
            e0_Wih, e0_Whh, e0_bih, e0_bhh,
            e1_Wih, e1_Whh, e1_bih, e1_bhh,
            h0buf, c0, h1buf, c1, ring, keys);
    }

    // ---- decoder init + keys_proj ----
    dec_init<<<(B * H + 255) / 256, 256, 0, stream>>>(h0buf, c0, h1buf, c1, hist,
                                                      hd1, cd1, hd2, cd2, curr);
    keysproj<<<(B * NKEYS) / 32, 256, 0, stream>>>(keys, aW_w, aW_b, kp);

    // ---- decoder loop ----
    for (int t = 0; t < T_FUT; ++t) {
        const float* hd1_r = hd1 + (size_t)(t & 1) * BH;
        float*       hd1_w = hd1 + (size_t)((t + 1) & 1) * BH;
        const float* hd2_r = hd2 + (size_t)(t & 1) * BH;
        float*       hd2_w = hd2 + (size_t)((t + 1) & 1) * BH;
        dec_attn<<<B, 256, 0, stream>>>(t, keys, kp, aW_w, av_w, av_b, o_w, o_b,
                                        hd2_r, curr, ctx, preds);
        dec_cell0<<<H, 128, 0, stream>>>(d0_Wih, d0_Whh, d0_bih, d0_bhh,
                                         curr, ctx, hd1_r, hd1_w, cd1);
        dec_cell1<<<H, 128, 0, stream>>>(d1_Wih, d1_Whh, d1_bih, d1_bhh,
                                         hd1_w, hd2_r, hd2_w, cd2);
    }
    final_out<<<1, 256, 0, stream>>>(hd2 + (size_t)(T_FUT & 1) * BH, o_w, o_b, curr, preds);
}